// Round 1
// baseline (70544.397 us; speedup 1.0000x reference)
//
#include <hip/hip_runtime.h>
#include <stdint.h>

// RBNN: T=1024 sequential spiking steps. Phase B (sequential): pre/ad/spike
// recurrence, 2 kernels per step, pure fp32 ascending-k fmaf (flip-sensitive).
// Phase C (parallel over t): post + out GEMMs from bitpacked spike history.
// ws ~25 MB: spk_bits [1025][1024] u64, post_bits [1024][2048] u64,
//            spk_u8 [64][1024], pre_u8 [64][2048].

#define TT 1024
#define BB 64
#define NIc 512
#define NPREc 2048
#define NADc 1024
#define NPOSTc 2048
#define NOUTc 512
#define KXc 1536   // NI + NAD

typedef unsigned long long u64;

// ---------- init: spikes0 = [zeros(512), ones(512)] ----------
__global__ __launch_bounds__(256) void k_init(u64* __restrict__ spk_bits,
                                              uint8_t* __restrict__ spk_u8) {
  int tid = blockIdx.x * 256 + threadIdx.x;  // 65536 threads
  int b = tid >> 10, i = tid & 1023;
  spk_u8[b * NADc + i] = (uint8_t)((i < 512) ? 0 : 1);
  if (tid < NADc) spk_bits[tid] = (tid < 512) ? 0ull : ~0ull;
}

// ---------- stage1: pre[b,j] = spike(x @ W_pre.T + b_pre) ----------
// wave = j-pair, lane = batch row. Scalar (wave-uniform) weight loads.
__global__ __launch_bounds__(256) void k_stage1(
    const float* __restrict__ inp, const float* __restrict__ W_pre,
    const float* __restrict__ b_pre, const uint8_t* __restrict__ spk_u8,
    uint8_t* __restrict__ pre_u8, int t) {
  const int lane = threadIdx.x & 63;
  const int wave = threadIdx.x >> 6;
  int j0 = (blockIdx.x * 4 + wave) * 2;
  j0 = __builtin_amdgcn_readfirstlane(j0);
  const int b = lane;
  const float* xrow = inp + ((size_t)t * BB + b) * NIc;
  const float* w0 = W_pre + (size_t)j0 * KXc;
  const float* w1 = w0 + KXc;
  const uint8_t* srow = spk_u8 + b * NADc;
  float a0 = 0.f, a1 = 0.f;
  // input part: k = 0..511 (matches concat([inp_t, spikes]) order)
  for (int i = 0; i < NIc; i += 4) {
    float4 x = *(const float4*)(xrow + i);
    float4 p = *(const float4*)(w0 + i);
    float4 q = *(const float4*)(w1 + i);
    a0 = fmaf(x.x, p.x, a0); a0 = fmaf(x.y, p.y, a0);
    a0 = fmaf(x.z, p.z, a0); a0 = fmaf(x.w, p.w, a0);
    a1 = fmaf(x.x, q.x, a1); a1 = fmaf(x.y, q.y, a1);
    a1 = fmaf(x.z, q.z, a1); a1 = fmaf(x.w, q.w, a1);
  }
  // spike part: k = 512..1535
  for (int k = 0; k < NADc; k += 4) {
    uchar4 xc = *(const uchar4*)(srow + k);
    float x0 = (float)xc.x, x1 = (float)xc.y, x2 = (float)xc.z, x3 = (float)xc.w;
    float4 p = *(const float4*)(w0 + NIc + k);
    float4 q = *(const float4*)(w1 + NIc + k);
    a0 = fmaf(x0, p.x, a0); a0 = fmaf(x1, p.y, a0);
    a0 = fmaf(x2, p.z, a0); a0 = fmaf(x3, p.w, a0);
    a1 = fmaf(x0, q.x, a1); a1 = fmaf(x1, q.y, a1);
    a1 = fmaf(x2, q.z, a1); a1 = fmaf(x3, q.w, a1);
  }
  float s0 = a0 + b_pre[j0];
  float s1 = a1 + b_pre[j0 + 1];
  uint16_t pk = (uint16_t)((s0 > 0.f) ? 1u : 0u) |
                (uint16_t)(((s1 > 0.f) ? 1u : 0u) << 8);
  *(uint16_t*)(pre_u8 + b * NPREc + j0) = pk;
}

// ---------- stage2: ad = pre @ W_ad.T + b_ad; spk' = spike(ad + 0.5*spk) ----
// wave = one output neuron i, lane = batch row.
__global__ __launch_bounds__(256) void k_stage2(
    const float* __restrict__ W_ad, const float* __restrict__ b_ad,
    const uint8_t* __restrict__ pre_u8, const u64* __restrict__ spk_bits_old,
    u64* __restrict__ spk_bits_next, uint8_t* __restrict__ spk_u8) {
  const int lane = threadIdx.x & 63;
  const int wave = threadIdx.x >> 6;
  int i = blockIdx.x * 4 + wave;
  i = __builtin_amdgcn_readfirstlane(i);
  const int b = lane;
  const float* wrow = W_ad + (size_t)i * NPREc;
  const uint8_t* prow = pre_u8 + b * NPREc;
  float a = 0.f;
  for (int j = 0; j < NPREc; j += 4) {
    uchar4 xc = *(const uchar4*)(prow + j);
    float4 w = *(const float4*)(wrow + j);
    a = fmaf((float)xc.x, w.x, a); a = fmaf((float)xc.y, w.y, a);
    a = fmaf((float)xc.z, w.z, a); a = fmaf((float)xc.w, w.w, a);
  }
  float ad = a + b_ad[i];
  u64 ow = spk_bits_old[i];
  float os = (float)((unsigned)(ow >> b) & 1u);
  float v = ad + 0.5f * os;
  int nb = (v > 0.f) ? 1 : 0;
  u64 mask = __ballot(nb);
  if (lane == 0) spk_bits_next[i] = mask;
  spk_u8[b * NADc + i] = (uint8_t)nb;
}

// ---------- phase C1: post bits for all t ----------
// grid (t, jc); wave = 16 consecutive j, lane = batch row.
__global__ __launch_bounds__(256) void k_post(
    const float* __restrict__ inp, const float* __restrict__ W_post,
    const float* __restrict__ b_post, const u64* __restrict__ spk_bits,
    u64* __restrict__ post_bits) {
  const int t = blockIdx.x;
  const int lane = threadIdx.x & 63;
  const int wave = threadIdx.x >> 6;
  int j0 = (blockIdx.y * 4 + wave) * 16;
  j0 = __builtin_amdgcn_readfirstlane(j0);
  const int b = lane;
  const float* xrow = inp + ((size_t)t * BB + b) * NIc;
  const u64* sbits = spk_bits + (size_t)(t + 1) * NADc;  // new spikes of step t
  const float* wbase = W_post + (size_t)j0 * KXc;
  float acc[16];
#pragma unroll
  for (int q = 0; q < 16; ++q) acc[q] = 0.f;
  for (int i = 0; i < NIc; i += 4) {
    float4 x = *(const float4*)(xrow + i);
#pragma unroll
    for (int q = 0; q < 16; ++q) {
      float4 w = *(const float4*)(wbase + (size_t)q * KXc + i);
      acc[q] = fmaf(x.x, w.x, acc[q]); acc[q] = fmaf(x.y, w.y, acc[q]);
      acc[q] = fmaf(x.z, w.z, acc[q]); acc[q] = fmaf(x.w, w.w, acc[q]);
    }
  }
  for (int k = 0; k < NADc; k += 4) {
    float xs0 = (float)((unsigned)(sbits[k + 0] >> b) & 1u);
    float xs1 = (float)((unsigned)(sbits[k + 1] >> b) & 1u);
    float xs2 = (float)((unsigned)(sbits[k + 2] >> b) & 1u);
    float xs3 = (float)((unsigned)(sbits[k + 3] >> b) & 1u);
#pragma unroll
    for (int q = 0; q < 16; ++q) {
      float4 w = *(const float4*)(wbase + (size_t)q * KXc + NIc + k);
      acc[q] = fmaf(xs0, w.x, acc[q]); acc[q] = fmaf(xs1, w.y, acc[q]);
      acc[q] = fmaf(xs2, w.z, acc[q]); acc[q] = fmaf(xs3, w.w, acc[q]);
    }
  }
#pragma unroll
  for (int q = 0; q < 16; ++q) {
    float s = acc[q] + b_post[j0 + q];
    u64 m = __ballot(s > 0.f);
    if (lane == 0) post_bits[(size_t)t * NPOSTc + j0 + q] = m;
  }
}

// ---------- phase C2: o = post @ W_out.T + b_out ----------
// grid (t, nc); wave = 16 consecutive n, lane = batch row.
__global__ __launch_bounds__(256) void k_out(
    const float* __restrict__ W_out, const float* __restrict__ b_out,
    const u64* __restrict__ post_bits, float* __restrict__ out) {
  const int t = blockIdx.x;
  const int lane = threadIdx.x & 63;
  const int wave = threadIdx.x >> 6;
  int n0 = (blockIdx.y * 4 + wave) * 16;
  n0 = __builtin_amdgcn_readfirstlane(n0);
  const int b = lane;
  const u64* pb = post_bits + (size_t)t * NPOSTc;
  const float* wbase = W_out + (size_t)n0 * NPOSTc;
  float acc[16];
#pragma unroll
  for (int q = 0; q < 16; ++q) acc[q] = 0.f;
  for (int j = 0; j < NPOSTc; j += 4) {
    float xs0 = (float)((unsigned)(pb[j + 0] >> b) & 1u);
    float xs1 = (float)((unsigned)(pb[j + 1] >> b) & 1u);
    float xs2 = (float)((unsigned)(pb[j + 2] >> b) & 1u);
    float xs3 = (float)((unsigned)(pb[j + 3] >> b) & 1u);
#pragma unroll
    for (int q = 0; q < 16; ++q) {
      float4 w = *(const float4*)(wbase + (size_t)q * NPOSTc + j);
      acc[q] = fmaf(xs0, w.x, acc[q]); acc[q] = fmaf(xs1, w.y, acc[q]);
      acc[q] = fmaf(xs2, w.z, acc[q]); acc[q] = fmaf(xs3, w.w, acc[q]);
    }
  }
  float* orow = out + ((size_t)t * BB + b) * NOUTc;
#pragma unroll
  for (int q = 0; q < 16; ++q) orow[n0 + q] = acc[q] + b_out[n0 + q];
}

// ---------- final_spikes -> d_out tail ----------
__global__ __launch_bounds__(256) void k_final(const u64* __restrict__ spk_last,
                                               float* __restrict__ out_tail) {
  int tid = blockIdx.x * 256 + threadIdx.x;  // 65536
  int b = tid >> 10, i = tid & 1023;
  out_tail[tid] = (float)((unsigned)(spk_last[i] >> b) & 1u);
}

extern "C" void kernel_launch(void* const* d_in, const int* in_sizes, int n_in,
                              void* d_out, int out_size, void* d_ws, size_t ws_size,
                              hipStream_t stream) {
  const float* inp    = (const float*)d_in[0];
  const float* W_pre  = (const float*)d_in[1];
  const float* b_pre  = (const float*)d_in[2];
  const float* W_ad   = (const float*)d_in[3];
  const float* b_ad   = (const float*)d_in[4];
  const float* W_post = (const float*)d_in[5];
  const float* b_post = (const float*)d_in[6];
  const float* W_out  = (const float*)d_in[7];
  const float* b_out  = (const float*)d_in[8];
  float* out = (float*)d_out;

  char* ws = (char*)d_ws;
  u64* spk_bits  = (u64*)ws;                               // [1025][1024] = 8,396,800 B
  u64* post_bits = (u64*)(ws + 8396800);                   // [1024][2048] = 16,777,216 B
  uint8_t* spk_u8 = (uint8_t*)(ws + 8396800 + 16777216);   // [64][1024]
  uint8_t* pre_u8 = spk_u8 + 65536;                        // [64][2048]

  k_init<<<256, 256, 0, stream>>>(spk_bits, spk_u8);

  for (int t = 0; t < TT; ++t) {
    k_stage1<<<256, 256, 0, stream>>>(inp, W_pre, b_pre, spk_u8, pre_u8, t);
    k_stage2<<<256, 256, 0, stream>>>(W_ad, b_ad, pre_u8,
                                      spk_bits + (size_t)t * NADc,
                                      spk_bits + (size_t)(t + 1) * NADc,
                                      spk_u8);
  }

  k_post<<<dim3(TT, 32), 256, 0, stream>>>(inp, W_post, b_post, spk_bits, post_bits);
  k_out<<<dim3(TT, 8), 256, 0, stream>>>(W_out, b_out, post_bits, out);
  k_final<<<256, 256, 0, stream>>>(spk_bits + (size_t)TT * NADc,
                                   out + (size_t)TT * BB * NOUTc);
}